// Round 1
// baseline (2968.985 us; speedup 1.0000x reference)
//
#include <hip/hip_runtime.h>
#include <hip/hip_bf16.h>

#define DIM 128

// ---------------- degree: deg[dst] += 1 ----------------
__global__ __launch_bounds__(256) void degree_kernel(
    const int* __restrict__ dst, float* __restrict__ deg, int E)
{
    int e = blockIdx.x * 256 + threadIdx.x;
    if (e < E) atomicAdd(&deg[dst[e]], 1.0f);
}

// ---------------- scatter: msg[dst] += x[src], 4 features per thread ----------------
__global__ __launch_bounds__(256) void scatter_kernel(
    const float* __restrict__ xin, const int* __restrict__ src,
    const int* __restrict__ dst, float* __restrict__ msg, long long total)
{
    long long idx = (long long)blockIdx.x * 256 + threadIdx.x;   // E*32 threads
    if (idx >= total) return;
    int e = (int)(idx >> 5);
    int q = (int)(idx & 31);                                     // feature quad
    int s = src[e], d = dst[e];
    const float4 v = *reinterpret_cast<const float4*>(&xin[(size_t)s * DIM + q * 4]);
    float* p = &msg[(size_t)d * DIM + q * 4];
    atomicAdd(p + 0, v.x);
    atomicAdd(p + 1, v.y);
    atomicAdd(p + 2, v.z);
    atomicAdd(p + 3, v.w);
}

// ---------------- fused SAGE dense: out = relu(mean(msg,deg)@Wl + xin@Wr + b) ----------------
// 32 nodes per block, 256 threads: thread t -> f = t&127, node-row group nr = t>>7.
// Node features staged in LDS (all reads are wave-broadcast: conflict-free).
__global__ __launch_bounds__(256) void sage_dense(
    const float* __restrict__ msg, const float* __restrict__ deg,
    const float* __restrict__ xin,
    const float* __restrict__ Wl, const float* __restrict__ Wr,
    const float* __restrict__ bias, float* __restrict__ out, int n)
{
    __shared__ float s_mean[32 * DIM];
    __shared__ float s_x[32 * DIM];
    const int t = threadIdx.x;
    const int node0 = blockIdx.x * 32;

    for (int idx = t; idx < 32 * DIM; idx += 256) {
        int nd = idx >> 7, k = idx & 127;
        int node = node0 + nd;
        float m = 0.f, xv = 0.f;
        if (node < n) {
            float r = 1.0f / fmaxf(deg[node], 1.0f);
            m  = msg[(size_t)node * DIM + k] * r;
            xv = xin[(size_t)node * DIM + k];
        }
        s_mean[idx] = m;
        s_x[idx]    = xv;
    }
    __syncthreads();

    const int f  = t & 127;
    const int nr = t >> 7;   // 0 or 1 -> nodes nr*16 .. nr*16+15
    float acc[16];
    const float bv = bias[f];
#pragma unroll
    for (int i = 0; i < 16; ++i) acc[i] = bv;

    for (int k0 = 0; k0 < DIM; k0 += 4) {
        float wl[4], wr[4];
#pragma unroll
        for (int j = 0; j < 4; ++j) {
            wl[j] = Wl[(k0 + j) * DIM + f];
            wr[j] = Wr[(k0 + j) * DIM + f];
        }
#pragma unroll
        for (int i = 0; i < 16; ++i) {
            const int nd = nr * 16 + i;
            const float4 m4 = *reinterpret_cast<const float4*>(&s_mean[nd * DIM + k0]);
            const float4 x4 = *reinterpret_cast<const float4*>(&s_x[nd * DIM + k0]);
            acc[i] += m4.x * wl[0] + m4.y * wl[1] + m4.z * wl[2] + m4.w * wl[3]
                    + x4.x * wr[0] + x4.y * wr[1] + x4.z * wr[2] + x4.w * wr[3];
        }
    }

#pragma unroll
    for (int i = 0; i < 16; ++i) {
        const int nd = nr * 16 + i;
        const int node = node0 + nd;
        if (node < n) {
            out[(size_t)node * DIM + f] = fmaxf(acc[i], 0.0f);
        }
    }
}

// ---------------- head: out[i][o] = sum_k h[i][k]*Wh[k][o] + bh[o], o in {0,1} ----------------
__global__ __launch_bounds__(256) void head_kernel(
    const float* __restrict__ h, const float* __restrict__ Wh,
    const float* __restrict__ bh, float* __restrict__ out, int n)
{
    const int t = threadIdx.x;
    const int lane = t & 63;
    const int w = t >> 6;
    const int node = blockIdx.x * 4 + w;
    if (node >= n) return;
    const float a = h[(size_t)node * DIM + lane];
    const float b = h[(size_t)node * DIM + 64 + lane];
    float p0 = a * Wh[lane * 2 + 0] + b * Wh[(lane + 64) * 2 + 0];
    float p1 = a * Wh[lane * 2 + 1] + b * Wh[(lane + 64) * 2 + 1];
#pragma unroll
    for (int off = 32; off > 0; off >>= 1) {
        p0 += __shfl_down(p0, off, 64);
        p1 += __shfl_down(p1, off, 64);
    }
    if (lane == 0) {
        out[(size_t)node * 2 + 0] = p0 + bh[0];
        out[(size_t)node * 2 + 1] = p1 + bh[1];
    }
}

extern "C" void kernel_launch(void* const* d_in, const int* in_sizes, int n_in,
                              void* d_out, int out_size, void* d_ws, size_t ws_size,
                              hipStream_t stream) {
    const float* x    = (const float*)d_in[0];
    const int*   ei   = (const int*)d_in[1];
    const float* W1l  = (const float*)d_in[2];
    const float* W1r  = (const float*)d_in[3];
    const float* b1   = (const float*)d_in[4];
    const float* W2l  = (const float*)d_in[5];
    const float* W2r  = (const float*)d_in[6];
    const float* b2   = (const float*)d_in[7];
    const float* Wh   = (const float*)d_in[8];
    const float* bh   = (const float*)d_in[9];
    float* out = (float*)d_out;

    const int n = in_sizes[0] / DIM;      // 50000
    const int E = in_sizes[1] / 2;        // 800000
    const int* src = ei;
    const int* dst = ei + E;

    char* ws = (char*)d_ws;
    float* deg = (float*)ws;
    size_t offA = (((size_t)n * 4 + 511) / 512) * 512;
    float* bufA = (float*)(ws + offA);                              // [n,128] msg / h2
    float* bufB = (float*)(ws + offA + (size_t)n * DIM * 4);        // [n,128] h1

    hipMemsetAsync(deg, 0, (size_t)n * 4, stream);
    hipMemsetAsync(bufA, 0, (size_t)n * DIM * 4, stream);

    degree_kernel<<<(E + 255) / 256, 256, 0, stream>>>(dst, deg, E);

    const long long tot = (long long)E * 32;
    const int sgrid = (int)((tot + 255) / 256);
    const int dgrid = (n + 31) / 32;

    // layer 1
    scatter_kernel<<<sgrid, 256, 0, stream>>>(x, src, dst, bufA, tot);
    sage_dense<<<dgrid, 256, 0, stream>>>(bufA, deg, x, W1l, W1r, b1, bufB, n);

    // layer 2
    hipMemsetAsync(bufA, 0, (size_t)n * DIM * 4, stream);
    scatter_kernel<<<sgrid, 256, 0, stream>>>(bufB, src, dst, bufA, tot);
    sage_dense<<<dgrid, 256, 0, stream>>>(bufA, deg, bufB, W2l, W2r, b2, bufA, n);

    // head
    head_kernel<<<(n + 3) / 4, 256, 0, stream>>>(bufA, Wh, bh, out, n);
}

// Round 2
// 391.459 us; speedup vs baseline: 7.5844x; 7.5844x over previous
//
#include <hip/hip_runtime.h>
#include <hip/hip_bf16.h>

#define DIM 128

// ---------------- degree: deg[dst] += 1 (int) ----------------
__global__ __launch_bounds__(256) void degree_kernel(
    const int* __restrict__ dst, int* __restrict__ deg, int E)
{
    int e = blockIdx.x * 256 + threadIdx.x;
    if (e < E) atomicAdd(&deg[dst[e]], 1);
}

// ---------------- per-block partial sums of deg ----------------
__global__ __launch_bounds__(256) void partial_kernel(
    const int* __restrict__ deg, int* __restrict__ partial, int n)
{
    __shared__ int s[256];
    const int t = threadIdx.x;
    const int i = blockIdx.x * 256 + t;
    s[t] = (i < n) ? deg[i] : 0;
    __syncthreads();
    for (int off = 128; off > 0; off >>= 1) {
        if (t < off) s[t] += s[t + off];
        __syncthreads();
    }
    if (t == 0) partial[blockIdx.x] = s[0];
}

// ---------------- scan the block partials (nblk <= 256) ----------------
__global__ __launch_bounds__(256) void scan_partials(
    const int* __restrict__ partial, int* __restrict__ blockoff,
    int nblk, int* __restrict__ rowptr, int n)
{
    __shared__ int s[256];
    const int t = threadIdx.x;
    const int v = (t < nblk) ? partial[t] : 0;
    s[t] = v;
    __syncthreads();
    for (int off = 1; off < 256; off <<= 1) {
        int a = (t >= off) ? s[t - off] : 0;
        __syncthreads();
        s[t] += a;
        __syncthreads();
    }
    if (t < nblk) blockoff[t] = s[t] - v;     // exclusive
    if (t == 255) rowptr[n] = s[255];         // total == E
}

// ---------------- local scan: rowptr / cursor ----------------
__global__ __launch_bounds__(256) void local_scan(
    const int* __restrict__ deg, const int* __restrict__ blockoff,
    int* __restrict__ rowptr, int* __restrict__ cursor, int n)
{
    __shared__ int s[256];
    const int t = threadIdx.x;
    const int i = blockIdx.x * 256 + t;
    const int v = (i < n) ? deg[i] : 0;
    s[t] = v;
    __syncthreads();
    for (int off = 1; off < 256; off <<= 1) {
        int a = (t >= off) ? s[t - off] : 0;
        __syncthreads();
        s[t] += a;
        __syncthreads();
    }
    if (i < n) {
        int excl = blockoff[blockIdx.x] + s[t] - v;
        rowptr[i] = excl;
        cursor[i] = excl;
    }
}

// ---------------- fill CSR: csr_src[pos] = src[e] ----------------
__global__ __launch_bounds__(256) void fill_kernel(
    const int* __restrict__ src, const int* __restrict__ dst,
    int* __restrict__ cursor, int* __restrict__ csr_src, int E)
{
    int e = blockIdx.x * 256 + threadIdx.x;
    if (e < E) {
        int d = dst[e];
        int pos = atomicAdd(&cursor[d], 1);
        csr_src[pos] = src[e];
    }
}

// ---------------- gather mean: one wave per node, float2 per lane ----------------
__global__ __launch_bounds__(256) void gather_mean(
    const float* __restrict__ x, const int* __restrict__ rowptr,
    const int* __restrict__ csr_src, float* __restrict__ mean, int n)
{
    const int node = (blockIdx.x * 256 + threadIdx.x) >> 6;
    const int lane = threadIdx.x & 63;
    if (node >= n) return;
    const int beg = rowptr[node], end = rowptr[node + 1];
    const float2* xv = (const float2*)x;
    float ax = 0.f, ay = 0.f;
    int i = beg;
    for (; i + 4 <= end; i += 4) {
        int s0 = csr_src[i], s1 = csr_src[i + 1], s2 = csr_src[i + 2], s3 = csr_src[i + 3];
        float2 v0 = xv[(size_t)s0 * 64 + lane];
        float2 v1 = xv[(size_t)s1 * 64 + lane];
        float2 v2 = xv[(size_t)s2 * 64 + lane];
        float2 v3 = xv[(size_t)s3 * 64 + lane];
        ax += v0.x + v1.x + v2.x + v3.x;
        ay += v0.y + v1.y + v2.y + v3.y;
    }
    for (; i < end; ++i) {
        int s0 = csr_src[i];
        float2 v = xv[(size_t)s0 * 64 + lane];
        ax += v.x; ay += v.y;
    }
    const float r = 1.0f / fmaxf((float)(end - beg), 1.0f);
    float2 o; o.x = ax * r; o.y = ay * r;
    ((float2*)mean)[(size_t)node * 64 + lane] = o;
}

// ---------------- fused SAGE dense: out = relu(mean@Wl + xin@Wr + b) ----------------
// In-place safe when out == mean (rows staged into LDS before any write).
__global__ __launch_bounds__(256) void sage_dense(
    const float* __restrict__ mean, const float* __restrict__ xin,
    const float* __restrict__ Wl, const float* __restrict__ Wr,
    const float* __restrict__ bias, float* __restrict__ out, int n)
{
    __shared__ float s_mean[32 * DIM];
    __shared__ float s_x[32 * DIM];
    const int t = threadIdx.x;
    const int node0 = blockIdx.x * 32;

    for (int idx = t; idx < 32 * DIM; idx += 256) {
        int nd = idx >> 7, k = idx & 127;
        int node = node0 + nd;
        float m = 0.f, xv = 0.f;
        if (node < n) {
            m  = mean[(size_t)node * DIM + k];
            xv = xin[(size_t)node * DIM + k];
        }
        s_mean[idx] = m;
        s_x[idx]    = xv;
    }
    __syncthreads();

    const int f  = t & 127;
    const int nr = t >> 7;
    float acc[16];
    const float bv = bias[f];
#pragma unroll
    for (int i = 0; i < 16; ++i) acc[i] = bv;

    for (int k0 = 0; k0 < DIM; k0 += 4) {
        float wl[4], wr[4];
#pragma unroll
        for (int j = 0; j < 4; ++j) {
            wl[j] = Wl[(k0 + j) * DIM + f];
            wr[j] = Wr[(k0 + j) * DIM + f];
        }
#pragma unroll
        for (int i = 0; i < 16; ++i) {
            const int nd = nr * 16 + i;
            const float4 m4 = *reinterpret_cast<const float4*>(&s_mean[nd * DIM + k0]);
            const float4 x4 = *reinterpret_cast<const float4*>(&s_x[nd * DIM + k0]);
            acc[i] += m4.x * wl[0] + m4.y * wl[1] + m4.z * wl[2] + m4.w * wl[3]
                    + x4.x * wr[0] + x4.y * wr[1] + x4.z * wr[2] + x4.w * wr[3];
        }
    }

#pragma unroll
    for (int i = 0; i < 16; ++i) {
        const int nd = nr * 16 + i;
        const int node = node0 + nd;
        if (node < n) {
            out[(size_t)node * DIM + f] = fmaxf(acc[i], 0.0f);
        }
    }
}

// ---------------- head ----------------
__global__ __launch_bounds__(256) void head_kernel(
    const float* __restrict__ h, const float* __restrict__ Wh,
    const float* __restrict__ bh, float* __restrict__ out, int n)
{
    const int t = threadIdx.x;
    const int lane = t & 63;
    const int w = t >> 6;
    const int node = blockIdx.x * 4 + w;
    if (node >= n) return;
    const float a = h[(size_t)node * DIM + lane];
    const float b = h[(size_t)node * DIM + 64 + lane];
    float p0 = a * Wh[lane * 2 + 0] + b * Wh[(lane + 64) * 2 + 0];
    float p1 = a * Wh[lane * 2 + 1] + b * Wh[(lane + 64) * 2 + 1];
#pragma unroll
    for (int off = 32; off > 0; off >>= 1) {
        p0 += __shfl_down(p0, off, 64);
        p1 += __shfl_down(p1, off, 64);
    }
    if (lane == 0) {
        out[(size_t)node * 2 + 0] = p0 + bh[0];
        out[(size_t)node * 2 + 1] = p1 + bh[1];
    }
}

extern "C" void kernel_launch(void* const* d_in, const int* in_sizes, int n_in,
                              void* d_out, int out_size, void* d_ws, size_t ws_size,
                              hipStream_t stream) {
    const float* x    = (const float*)d_in[0];
    const int*   ei   = (const int*)d_in[1];
    const float* W1l  = (const float*)d_in[2];
    const float* W1r  = (const float*)d_in[3];
    const float* b1   = (const float*)d_in[4];
    const float* W2l  = (const float*)d_in[5];
    const float* W2r  = (const float*)d_in[6];
    const float* b2   = (const float*)d_in[7];
    const float* Wh   = (const float*)d_in[8];
    const float* bh   = (const float*)d_in[9];
    float* out = (float*)d_out;

    const int n = in_sizes[0] / DIM;      // 50000
    const int E = in_sizes[1] / 2;        // 800000
    const int* src = ei;
    const int* dst = ei + E;

    auto align512 = [](size_t v) { return (v + 511) & ~(size_t)511; };
    char* ws = (char*)d_ws;
    size_t off = 0;
    int* deg      = (int*)(ws + off); off = align512(off + (size_t)n * 4);
    int* rowptr   = (int*)(ws + off); off = align512(off + (size_t)(n + 1) * 4);
    int* cursor   = (int*)(ws + off); off = align512(off + (size_t)n * 4);
    int* partial  = (int*)(ws + off); off = align512(off + 256 * 4);
    int* blockoff = (int*)(ws + off); off = align512(off + 256 * 4);
    int* csr_src  = (int*)(ws + off); off = align512(off + (size_t)E * 4);
    float* bufA   = (float*)(ws + off); off = align512(off + (size_t)n * DIM * 4);
    float* bufB   = (float*)(ws + off); off = align512(off + (size_t)n * DIM * 4);

    const int nblk  = (n + 255) / 256;        // 196
    const int egrid = (E + 255) / 256;
    const int dgrid = (n + 31) / 32;
    const int ggrid = (n + 3) / 4;            // 4 waves/block, 1 node/wave

    // ---- build CSR (once) ----
    hipMemsetAsync(deg, 0, (size_t)n * 4, stream);
    degree_kernel<<<egrid, 256, 0, stream>>>(dst, deg, E);
    partial_kernel<<<nblk, 256, 0, stream>>>(deg, partial, n);
    scan_partials<<<1, 256, 0, stream>>>(partial, blockoff, nblk, rowptr, n);
    local_scan<<<nblk, 256, 0, stream>>>(deg, blockoff, rowptr, cursor, n);
    fill_kernel<<<egrid, 256, 0, stream>>>(src, dst, cursor, csr_src, E);

    // ---- layer 1: mean1 -> bufA; h1 = dense(bufA, x) in-place -> bufA ----
    gather_mean<<<ggrid, 256, 0, stream>>>(x, rowptr, csr_src, bufA, n);
    sage_dense<<<dgrid, 256, 0, stream>>>(bufA, x, W1l, W1r, b1, bufA, n);

    // ---- layer 2: mean2 = gather(bufA) -> bufB; h2 = dense(bufB, bufA) in-place -> bufB ----
    gather_mean<<<ggrid, 256, 0, stream>>>(bufA, rowptr, csr_src, bufB, n);
    sage_dense<<<dgrid, 256, 0, stream>>>(bufB, bufA, W2l, W2r, b2, bufB, n);

    // ---- head ----
    head_kernel<<<(n + 3) / 4, 256, 0, stream>>>(bufB, Wh, bh, out, n);
}

// Round 3
// 303.596 us; speedup vs baseline: 9.7794x; 1.2894x over previous
//
#include <hip/hip_runtime.h>
#include <hip/hip_bf16.h>

#define DIM 128

typedef short short8_t __attribute__((ext_vector_type(8)));
typedef float float4_t __attribute__((ext_vector_type(4)));

__device__ __forceinline__ unsigned short f2bf(float f) {
    __hip_bfloat16 h = __float2bfloat16(f);
    return *reinterpret_cast<unsigned short*>(&h);
}

// ---------------- degree: deg[dst] += 1 (int) ----------------
__global__ __launch_bounds__(256) void degree_kernel(
    const int* __restrict__ dst, int* __restrict__ deg, int E)
{
    int e = blockIdx.x * 256 + threadIdx.x;
    if (e < E) atomicAdd(&deg[dst[e]], 1);
}

// ---------------- per-block partial sums of deg ----------------
__global__ __launch_bounds__(256) void partial_kernel(
    const int* __restrict__ deg, int* __restrict__ partial, int n)
{
    __shared__ int s[256];
    const int t = threadIdx.x;
    const int i = blockIdx.x * 256 + t;
    s[t] = (i < n) ? deg[i] : 0;
    __syncthreads();
    for (int off = 128; off > 0; off >>= 1) {
        if (t < off) s[t] += s[t + off];
        __syncthreads();
    }
    if (t == 0) partial[blockIdx.x] = s[0];
}

// ---------------- scan the block partials (nblk <= 256) ----------------
__global__ __launch_bounds__(256) void scan_partials(
    const int* __restrict__ partial, int* __restrict__ blockoff,
    int nblk, int* __restrict__ rowptr, int n)
{
    __shared__ int s[256];
    const int t = threadIdx.x;
    const int v = (t < nblk) ? partial[t] : 0;
    s[t] = v;
    __syncthreads();
    for (int off = 1; off < 256; off <<= 1) {
        int a = (t >= off) ? s[t - off] : 0;
        __syncthreads();
        s[t] += a;
        __syncthreads();
    }
    if (t < nblk) blockoff[t] = s[t] - v;     // exclusive
    if (t == 255) rowptr[n] = s[255];         // total == E
}

// ---------------- local scan: rowptr / cursor ----------------
__global__ __launch_bounds__(256) void local_scan(
    const int* __restrict__ deg, const int* __restrict__ blockoff,
    int* __restrict__ rowptr, int* __restrict__ cursor, int n)
{
    __shared__ int s[256];
    const int t = threadIdx.x;
    const int i = blockIdx.x * 256 + t;
    const int v = (i < n) ? deg[i] : 0;
    s[t] = v;
    __syncthreads();
    for (int off = 1; off < 256; off <<= 1) {
        int a = (t >= off) ? s[t - off] : 0;
        __syncthreads();
        s[t] += a;
        __syncthreads();
    }
    if (i < n) {
        int excl = blockoff[blockIdx.x] + s[t] - v;
        rowptr[i] = excl;
        cursor[i] = excl;
    }
}

// ---------------- fill CSR: csr_src[pos] = src[e] ----------------
__global__ __launch_bounds__(256) void fill_kernel(
    const int* __restrict__ src, const int* __restrict__ dst,
    int* __restrict__ cursor, int* __restrict__ csr_src, int E)
{
    int e = blockIdx.x * 256 + threadIdx.x;
    if (e < E) {
        int d = dst[e];
        int pos = atomicAdd(&cursor[d], 1);
        csr_src[pos] = src[e];
    }
}

// ---------------- gather mean: one wave per node, float2 per lane ----------------
__global__ __launch_bounds__(256) void gather_mean(
    const float* __restrict__ x, const int* __restrict__ rowptr,
    const int* __restrict__ csr_src, float* __restrict__ mean, int n)
{
    const int node = (blockIdx.x * 256 + threadIdx.x) >> 6;
    const int lane = threadIdx.x & 63;
    if (node >= n) return;
    const int beg = rowptr[node], end = rowptr[node + 1];
    const float2* xv = (const float2*)x;
    float ax = 0.f, ay = 0.f;
    int i = beg;
    for (; i + 4 <= end; i += 4) {
        int s0 = csr_src[i], s1 = csr_src[i + 1], s2 = csr_src[i + 2], s3 = csr_src[i + 3];
        float2 v0 = xv[(size_t)s0 * 64 + lane];
        float2 v1 = xv[(size_t)s1 * 64 + lane];
        float2 v2 = xv[(size_t)s2 * 64 + lane];
        float2 v3 = xv[(size_t)s3 * 64 + lane];
        ax += v0.x + v1.x + v2.x + v3.x;
        ay += v0.y + v1.y + v2.y + v3.y;
    }
    for (; i < end; ++i) {
        int s0 = csr_src[i];
        float2 v = xv[(size_t)s0 * 64 + lane];
        ax += v.x; ay += v.y;
    }
    const float r = 1.0f / fmaxf((float)(end - beg), 1.0f);
    float2 o; o.x = ax * r; o.y = ay * r;
    ((float2*)mean)[(size_t)node * 64 + lane] = o;
}

// ---------------- weight prep: Wt[c][k] = bf16( k<128 ? Wl[k][c] : Wr[k-128][c] ) ----------------
__global__ __launch_bounds__(256) void wt_kernel(
    const float* __restrict__ Wl, const float* __restrict__ Wr,
    unsigned short* __restrict__ Wt)
{
    int idx = blockIdx.x * 256 + threadIdx.x;   // 128*256 = 32768
    if (idx >= 32768) return;
    int c = idx >> 8;
    int k = idx & 255;
    float v = (k < DIM) ? Wl[k * DIM + c] : Wr[(k - DIM) * DIM + c];
    Wt[c * 256 + k] = f2bf(v);
}

// ---------------- MFMA SAGE dense: out = relu([mean|x] @ [Wl;Wr] + b) ----------------
// 64 nodes/block, 4 waves; A staged in LDS as bf16, row-padded to 264 (2-way banks).
// In-place safe when out == mean (block only touches its own 64 rows, staged first).
__global__ __launch_bounds__(256) void sage_dense_mfma(
    const float* __restrict__ mean, const float* __restrict__ xin,
    const unsigned short* __restrict__ Wt,   // [128][256] bf16, feat-major
    const float* __restrict__ bias, float* __restrict__ out, int n)
{
    __shared__ unsigned short A_s[64 * 264];   // 33792 B
    const int t = threadIdx.x;
    const int node0 = blockIdx.x * 64;

    // stage A = [mean | x] -> bf16 LDS
    for (int idx = t; idx < 4096; idx += 256) {
        const int nd = idx >> 6;       // node in tile
        const int q  = idx & 63;       // feature quad (0..31 mean, 32..63 x)
        const int node = node0 + nd;
        float4 v = make_float4(0.f, 0.f, 0.f, 0.f);
        if (node < n) {
            v = (q < 32)
                ? *reinterpret_cast<const float4*>(&mean[(size_t)node * DIM + q * 4])
                : *reinterpret_cast<const float4*>(&xin[(size_t)node * DIM + (q - 32) * 4]);
        }
        uint2 p;
        p.x = (unsigned int)f2bf(v.x) | ((unsigned int)f2bf(v.y) << 16);
        p.y = (unsigned int)f2bf(v.z) | ((unsigned int)f2bf(v.w) << 16);
        *reinterpret_cast<uint2*>((char*)A_s + nd * 528 + q * 8) = p;
    }
    __syncthreads();

    const int wave = t >> 6;
    const int lane = t & 63;
    const int r = lane & 15;       // node-in-16 for A, feat-in-16 for B, col for D
    const int u = lane >> 4;       // k-block

    const char* a_base = (const char*)A_s + (wave * 16 + r) * 528 + u * 16;

    float4_t acc[8];
#pragma unroll
    for (int ft = 0; ft < 8; ++ft) acc[ft] = (float4_t){0.f, 0.f, 0.f, 0.f};

#pragma unroll
    for (int kk = 0; kk < 8; ++kk) {
        const short8_t a = *reinterpret_cast<const short8_t*>(a_base + kk * 64);
#pragma unroll
        for (int ft = 0; ft < 8; ++ft) {
            const short8_t b = *reinterpret_cast<const short8_t*>(
                &Wt[(ft * 16 + r) * 256 + kk * 32 + u * 8]);
            acc[ft] = __builtin_amdgcn_mfma_f32_16x16x32_bf16(a, b, acc[ft], 0, 0, 0);
        }
    }

    // epilogue: D row = u*4+j (node), col = r (feat)
#pragma unroll
    for (int ft = 0; ft < 8; ++ft) {
        const int feat = ft * 16 + r;
        const float bv = bias[feat];
#pragma unroll
        for (int j = 0; j < 4; ++j) {
            const int node = node0 + wave * 16 + u * 4 + j;
            if (node < n) {
                out[(size_t)node * DIM + feat] = fmaxf(acc[ft][j] + bv, 0.0f);
            }
        }
    }
}

// ---------------- head ----------------
__global__ __launch_bounds__(256) void head_kernel(
    const float* __restrict__ h, const float* __restrict__ Wh,
    const float* __restrict__ bh, float* __restrict__ out, int n)
{
    const int t = threadIdx.x;
    const int lane = t & 63;
    const int w = t >> 6;
    const int node = blockIdx.x * 4 + w;
    if (node >= n) return;
    const float a = h[(size_t)node * DIM + lane];
    const float b = h[(size_t)node * DIM + 64 + lane];
    float p0 = a * Wh[lane * 2 + 0] + b * Wh[(lane + 64) * 2 + 0];
    float p1 = a * Wh[lane * 2 + 1] + b * Wh[(lane + 64) * 2 + 1];
#pragma unroll
    for (int off = 32; off > 0; off >>= 1) {
        p0 += __shfl_down(p0, off, 64);
        p1 += __shfl_down(p1, off, 64);
    }
    if (lane == 0) {
        out[(size_t)node * 2 + 0] = p0 + bh[0];
        out[(size_t)node * 2 + 1] = p1 + bh[1];
    }
}

extern "C" void kernel_launch(void* const* d_in, const int* in_sizes, int n_in,
                              void* d_out, int out_size, void* d_ws, size_t ws_size,
                              hipStream_t stream) {
    const float* x    = (const float*)d_in[0];
    const int*   ei   = (const int*)d_in[1];
    const float* W1l  = (const float*)d_in[2];
    const float* W1r  = (const float*)d_in[3];
    const float* b1   = (const float*)d_in[4];
    const float* W2l  = (const float*)d_in[5];
    const float* W2r  = (const float*)d_in[6];
    const float* b2   = (const float*)d_in[7];
    const float* Wh   = (const float*)d_in[8];
    const float* bh   = (const float*)d_in[9];
    float* out = (float*)d_out;

    const int n = in_sizes[0] / DIM;      // 50000
    const int E = in_sizes[1] / 2;        // 800000
    const int* src = ei;
    const int* dst = ei + E;

    auto align512 = [](size_t v) { return (v + 511) & ~(size_t)511; };
    char* ws = (char*)d_ws;
    size_t off = 0;
    int* deg      = (int*)(ws + off); off = align512(off + (size_t)n * 4);
    int* rowptr   = (int*)(ws + off); off = align512(off + (size_t)(n + 1) * 4);
    int* cursor   = (int*)(ws + off); off = align512(off + (size_t)n * 4);
    int* partial  = (int*)(ws + off); off = align512(off + 256 * 4);
    int* blockoff = (int*)(ws + off); off = align512(off + 256 * 4);
    int* csr_src  = (int*)(ws + off); off = align512(off + (size_t)E * 4);
    unsigned short* Wt1 = (unsigned short*)(ws + off); off = align512(off + (size_t)32768 * 2);
    unsigned short* Wt2 = (unsigned short*)(ws + off); off = align512(off + (size_t)32768 * 2);
    float* bufA   = (float*)(ws + off); off = align512(off + (size_t)n * DIM * 4);
    float* bufB   = (float*)(ws + off); off = align512(off + (size_t)n * DIM * 4);

    const int nblk  = (n + 255) / 256;        // 196
    const int egrid = (E + 255) / 256;
    const int ggrid = (n + 3) / 4;            // 4 waves/block, 1 node/wave
    const int mgrid = (n + 63) / 64;          // MFMA dense blocks

    // ---- build CSR (once) + weight prep ----
    hipMemsetAsync(deg, 0, (size_t)n * 4, stream);
    degree_kernel<<<egrid, 256, 0, stream>>>(dst, deg, E);
    partial_kernel<<<nblk, 256, 0, stream>>>(deg, partial, n);
    scan_partials<<<1, 256, 0, stream>>>(partial, blockoff, nblk, rowptr, n);
    local_scan<<<nblk, 256, 0, stream>>>(deg, blockoff, rowptr, cursor, n);
    fill_kernel<<<egrid, 256, 0, stream>>>(src, dst, cursor, csr_src, E);
    wt_kernel<<<128, 256, 0, stream>>>(W1l, W1r, Wt1);
    wt_kernel<<<128, 256, 0, stream>>>(W2l, W2r, Wt2);

    // ---- layer 1: mean1 -> bufA; h1 = dense(bufA, x) in-place -> bufA ----
    gather_mean<<<ggrid, 256, 0, stream>>>(x, rowptr, csr_src, bufA, n);
    sage_dense_mfma<<<mgrid, 256, 0, stream>>>(bufA, x, Wt1, b1, bufA, n);

    // ---- layer 2: mean2 = gather(bufA) -> bufB; h2 = dense(bufB, bufA) in-place -> bufB ----
    gather_mean<<<ggrid, 256, 0, stream>>>(bufA, rowptr, csr_src, bufB, n);
    sage_dense_mfma<<<mgrid, 256, 0, stream>>>(bufB, bufA, Wt2, b2, bufB, n);

    // ---- head ----
    head_kernel<<<(n + 3) / 4, 256, 0, stream>>>(bufB, Wh, bh, out, n);
}

// Round 4
// 220.573 us; speedup vs baseline: 13.4603x; 1.3764x over previous
//
#include <hip/hip_runtime.h>
#include <hip/hip_bf16.h>

#define DIM 128

typedef short short8_t __attribute__((ext_vector_type(8)));
typedef float float4_t __attribute__((ext_vector_type(4)));

__device__ __forceinline__ unsigned short f2bf(float f) {
    __hip_bfloat16 h = __float2bfloat16(f);
    return *reinterpret_cast<unsigned short*>(&h);
}
__device__ __forceinline__ float bf2f(unsigned int lo16) {
    unsigned int v = lo16 << 16;
    return __uint_as_float(v);
}

// ---------------- rank+degree: rank[e] = old count of dst ----------------
__global__ __launch_bounds__(256) void rank_kernel(
    const int* __restrict__ dst, int* __restrict__ deg,
    int* __restrict__ rank, int E)
{
    int e = blockIdx.x * 256 + threadIdx.x;
    if (e < E) rank[e] = atomicAdd(&deg[dst[e]], 1);
}

// ---------------- per-block partial sums of deg ----------------
__global__ __launch_bounds__(256) void partial_kernel(
    const int* __restrict__ deg, int* __restrict__ partial, int n)
{
    __shared__ int s[256];
    const int t = threadIdx.x;
    const int i = blockIdx.x * 256 + t;
    s[t] = (i < n) ? deg[i] : 0;
    __syncthreads();
    for (int off = 128; off > 0; off >>= 1) {
        if (t < off) s[t] += s[t + off];
        __syncthreads();
    }
    if (t == 0) partial[blockIdx.x] = s[0];
}

// ---------------- scan the block partials (nblk <= 256) ----------------
__global__ __launch_bounds__(256) void scan_partials(
    const int* __restrict__ partial, int* __restrict__ blockoff,
    int nblk, int* __restrict__ rowptr, int n)
{
    __shared__ int s[256];
    const int t = threadIdx.x;
    const int v = (t < nblk) ? partial[t] : 0;
    s[t] = v;
    __syncthreads();
    for (int off = 1; off < 256; off <<= 1) {
        int a = (t >= off) ? s[t - off] : 0;
        __syncthreads();
        s[t] += a;
        __syncthreads();
    }
    if (t < nblk) blockoff[t] = s[t] - v;     // exclusive
    if (t == 255) rowptr[n] = s[255];         // total == E
}

// ---------------- local scan -> rowptr ----------------
__global__ __launch_bounds__(256) void local_scan(
    const int* __restrict__ deg, const int* __restrict__ blockoff,
    int* __restrict__ rowptr, int n)
{
    __shared__ int s[256];
    const int t = threadIdx.x;
    const int i = blockIdx.x * 256 + t;
    const int v = (i < n) ? deg[i] : 0;
    s[t] = v;
    __syncthreads();
    for (int off = 1; off < 256; off <<= 1) {
        int a = (t >= off) ? s[t - off] : 0;
        __syncthreads();
        s[t] += a;
        __syncthreads();
    }
    if (i < n) rowptr[i] = blockoff[blockIdx.x] + s[t] - v;
}

// ---------------- atomic-free CSR fill ----------------
__global__ __launch_bounds__(256) void scatter_fill(
    const int* __restrict__ src, const int* __restrict__ dst,
    const int* __restrict__ rank, const int* __restrict__ rowptr,
    int* __restrict__ csr_src, int E)
{
    int e = blockIdx.x * 256 + threadIdx.x;
    if (e < E) csr_src[rowptr[dst[e]] + rank[e]] = src[e];
}

// ---------------- fp32 -> bf16 conversion (4 elems/thread) ----------------
__global__ __launch_bounds__(256) void to_bf16(
    const float* __restrict__ in, unsigned short* __restrict__ out, int total4)
{
    int i = blockIdx.x * 256 + threadIdx.x;
    if (i < total4) {
        float4 v = reinterpret_cast<const float4*>(in)[i];
        uint2 p;
        p.x = (unsigned int)f2bf(v.x) | ((unsigned int)f2bf(v.y) << 16);
        p.y = (unsigned int)f2bf(v.z) | ((unsigned int)f2bf(v.w) << 16);
        reinterpret_cast<uint2*>(out)[i] = p;
    }
}

// ---------------- gather mean (bf16 in / bf16 out): one wave per node ----------------
__global__ __launch_bounds__(256) void gather_mean_bf(
    const unsigned short* __restrict__ xb, const int* __restrict__ rowptr,
    const int* __restrict__ csr_src, unsigned short* __restrict__ mean, int n)
{
    const int node = (blockIdx.x * 256 + threadIdx.x) >> 6;
    const int lane = threadIdx.x & 63;
    if (node >= n) return;
    const int beg = rowptr[node], end = rowptr[node + 1];
    const unsigned int* xv = (const unsigned int*)xb;   // 2 bf16 per uint, 64/row
    float ax = 0.f, ay = 0.f;
    int i = beg;
    for (; i + 4 <= end; i += 4) {
        int s0 = csr_src[i], s1 = csr_src[i + 1], s2 = csr_src[i + 2], s3 = csr_src[i + 3];
        unsigned int v0 = xv[(size_t)s0 * 64 + lane];
        unsigned int v1 = xv[(size_t)s1 * 64 + lane];
        unsigned int v2 = xv[(size_t)s2 * 64 + lane];
        unsigned int v3 = xv[(size_t)s3 * 64 + lane];
        ax += bf2f(v0 & 0xffffu) + bf2f(v1 & 0xffffu) + bf2f(v2 & 0xffffu) + bf2f(v3 & 0xffffu);
        ay += bf2f(v0 >> 16)     + bf2f(v1 >> 16)     + bf2f(v2 >> 16)     + bf2f(v3 >> 16);
    }
    for (; i < end; ++i) {
        unsigned int v = xv[(size_t)csr_src[i] * 64 + lane];
        ax += bf2f(v & 0xffffu);
        ay += bf2f(v >> 16);
    }
    const float r = 1.0f / fmaxf((float)(end - beg), 1.0f);
    unsigned int o = (unsigned int)f2bf(ax * r) | ((unsigned int)f2bf(ay * r) << 16);
    ((unsigned int*)mean)[(size_t)node * 64 + lane] = o;
}

// ---------------- weight prep: Wt[c][k] = bf16( k<128 ? Wl[k][c] : Wr[k-128][c] ) ----------------
__global__ __launch_bounds__(256) void wt_kernel(
    const float* __restrict__ Wl, const float* __restrict__ Wr,
    unsigned short* __restrict__ Wt)
{
    int idx = blockIdx.x * 256 + threadIdx.x;   // 128*256 = 32768
    if (idx >= 32768) return;
    int c = idx >> 8;
    int k = idx & 255;
    float v = (k < DIM) ? Wl[k * DIM + c] : Wr[(k - DIM) * DIM + c];
    Wt[c * 256 + k] = f2bf(v);
}

// ---------------- MFMA SAGE dense: relu([mean|x] @ [Wl;Wr] + b), optional fused head ----------------
// 64 nodes/block, 4 waves. A staged bf16 in LDS, row padded to 264 shorts.
template <bool FUSE_HEAD>
__global__ __launch_bounds__(256) void sage_dense_mfma(
    const unsigned short* __restrict__ meanB, const unsigned short* __restrict__ xinB,
    const unsigned short* __restrict__ Wt,    // [128][256] bf16, feat-major
    const float* __restrict__ bias,
    unsigned short* __restrict__ outB,        // !FUSE_HEAD: bf16 [n,128]
    const float* __restrict__ Wh, const float* __restrict__ bh,
    float* __restrict__ outH,                 // FUSE_HEAD: fp32 [n,2]
    int n)
{
    __shared__ unsigned short A_s[64 * 264];   // 33792 B
    const int t = threadIdx.x;
    const int node0 = blockIdx.x * 64;

    // stage A = [mean | x] (bf16): 64 rows x 32 chunks of 16B
    for (int idx = t; idx < 2048; idx += 256) {
        const int nd = idx >> 5;
        const int c  = idx & 31;
        const int node = node0 + nd;
        uint4 p = make_uint4(0, 0, 0, 0);
        if (node < n) {
            p = (c < 16) ? reinterpret_cast<const uint4*>(meanB)[(size_t)node * 16 + c]
                         : reinterpret_cast<const uint4*>(xinB)[(size_t)node * 16 + (c - 16)];
        }
        *reinterpret_cast<uint4*>((char*)A_s + nd * 528 + c * 16) = p;
    }
    __syncthreads();

    const int wave = t >> 6;
    const int lane = t & 63;
    const int r = lane & 15;       // node-in-16 for A / feat-in-16 for B / D col
    const int u = lane >> 4;       // k-block

    const char* a_base = (const char*)A_s + (wave * 16 + r) * 528 + u * 16;

    float4_t acc[8];
#pragma unroll
    for (int ft = 0; ft < 8; ++ft) acc[ft] = (float4_t){0.f, 0.f, 0.f, 0.f};

#pragma unroll
    for (int kk = 0; kk < 8; ++kk) {
        const short8_t a = *reinterpret_cast<const short8_t*>(a_base + kk * 64);
#pragma unroll
        for (int ft = 0; ft < 8; ++ft) {
            const short8_t b = *reinterpret_cast<const short8_t*>(
                &Wt[(ft * 16 + r) * 256 + kk * 32 + u * 8]);
            acc[ft] = __builtin_amdgcn_mfma_f32_16x16x32_bf16(a, b, acc[ft], 0, 0, 0);
        }
    }

    if (!FUSE_HEAD) {
        // h = relu(acc + bias) -> bf16 out
#pragma unroll
        for (int ft = 0; ft < 8; ++ft) {
            const int feat = ft * 16 + r;
            const float bv = bias[feat];
#pragma unroll
            for (int j = 0; j < 4; ++j) {
                const int node = node0 + wave * 16 + u * 4 + j;
                if (node < n) {
                    outB[(size_t)node * DIM + feat] = f2bf(fmaxf(acc[ft][j] + bv, 0.0f));
                }
            }
        }
    } else {
        // fused head: out[node][o] = sum_feat relu(h) * Wh[feat][o] + bh[o]
        float p0[4] = {0.f, 0.f, 0.f, 0.f};
        float p1[4] = {0.f, 0.f, 0.f, 0.f};
#pragma unroll
        for (int ft = 0; ft < 8; ++ft) {
            const int feat = ft * 16 + r;
            const float bv = bias[feat];
            const float w0 = Wh[feat * 2 + 0];
            const float w1 = Wh[feat * 2 + 1];
#pragma unroll
            for (int j = 0; j < 4; ++j) {
                const float h = fmaxf(acc[ft][j] + bv, 0.0f);
                p0[j] += h * w0;
                p1[j] += h * w1;
            }
        }
        // reduce across the 16 lanes sharing u (r = bits 0..3)
#pragma unroll
        for (int off = 1; off < 16; off <<= 1) {
#pragma unroll
            for (int j = 0; j < 4; ++j) {
                p0[j] += __shfl_xor(p0[j], off, 64);
                p1[j] += __shfl_xor(p1[j], off, 64);
            }
        }
        if (r == 0) {
            const float bh0 = bh[0], bh1 = bh[1];
#pragma unroll
            for (int j = 0; j < 4; ++j) {
                const int node = node0 + wave * 16 + u * 4 + j;
                if (node < n) {
                    outH[(size_t)node * 2 + 0] = p0[j] + bh0;
                    outH[(size_t)node * 2 + 1] = p1[j] + bh1;
                }
            }
        }
    }
}

extern "C" void kernel_launch(void* const* d_in, const int* in_sizes, int n_in,
                              void* d_out, int out_size, void* d_ws, size_t ws_size,
                              hipStream_t stream) {
    const float* x    = (const float*)d_in[0];
    const int*   ei   = (const int*)d_in[1];
    const float* W1l  = (const float*)d_in[2];
    const float* W1r  = (const float*)d_in[3];
    const float* b1   = (const float*)d_in[4];
    const float* W2l  = (const float*)d_in[5];
    const float* W2r  = (const float*)d_in[6];
    const float* b2   = (const float*)d_in[7];
    const float* Wh   = (const float*)d_in[8];
    const float* bh   = (const float*)d_in[9];
    float* out = (float*)d_out;

    const int n = in_sizes[0] / DIM;      // 50000
    const int E = in_sizes[1] / 2;        // 800000
    const int* src = ei;
    const int* dst = ei + E;

    auto align512 = [](size_t v) { return (v + 511) & ~(size_t)511; };
    char* ws = (char*)d_ws;
    size_t off = 0;
    int* deg      = (int*)(ws + off); off = align512(off + (size_t)n * 4);
    int* rowptr   = (int*)(ws + off); off = align512(off + (size_t)(n + 1) * 4);
    int* rank     = (int*)(ws + off); off = align512(off + (size_t)E * 4);
    int* partial  = (int*)(ws + off); off = align512(off + 256 * 4);
    int* blockoff = (int*)(ws + off); off = align512(off + 256 * 4);
    int* csr_src  = (int*)(ws + off); off = align512(off + (size_t)E * 4);
    unsigned short* Wt1 = (unsigned short*)(ws + off); off = align512(off + (size_t)32768 * 2);
    unsigned short* Wt2 = (unsigned short*)(ws + off); off = align512(off + (size_t)32768 * 2);
    unsigned short* xB   = (unsigned short*)(ws + off); off = align512(off + (size_t)n * DIM * 2);
    unsigned short* bufA = (unsigned short*)(ws + off); off = align512(off + (size_t)n * DIM * 2);
    unsigned short* bufB = (unsigned short*)(ws + off); off = align512(off + (size_t)n * DIM * 2);
    unsigned short* bufC = (unsigned short*)(ws + off); off = align512(off + (size_t)n * DIM * 2);

    const int nblk  = (n + 255) / 256;        // 196
    const int egrid = (E + 255) / 256;
    const int ggrid = (n + 3) / 4;            // 4 waves/block, 1 node/wave
    const int mgrid = (n + 63) / 64;          // MFMA dense blocks
    const int cgrid = ((n * DIM / 4) + 255) / 256;

    // ---- build CSR (atomic rank pass + scans + atomic-free fill) ----
    hipMemsetAsync(deg, 0, (size_t)n * 4, stream);
    rank_kernel<<<egrid, 256, 0, stream>>>(dst, deg, rank, E);
    partial_kernel<<<nblk, 256, 0, stream>>>(deg, partial, n);
    scan_partials<<<1, 256, 0, stream>>>(partial, blockoff, nblk, rowptr, n);
    local_scan<<<nblk, 256, 0, stream>>>(deg, blockoff, rowptr, n);
    scatter_fill<<<egrid, 256, 0, stream>>>(src, dst, rank, rowptr, csr_src, E);

    // ---- one-time conversions ----
    to_bf16<<<cgrid, 256, 0, stream>>>(x, xB, n * DIM / 4);
    wt_kernel<<<128, 256, 0, stream>>>(W1l, W1r, Wt1);
    wt_kernel<<<128, 256, 0, stream>>>(W2l, W2r, Wt2);

    // ---- layer 1: mean1 -> bufA; h1 = dense(bufA, xB) -> bufB (bf16) ----
    gather_mean_bf<<<ggrid, 256, 0, stream>>>(xB, rowptr, csr_src, bufA, n);
    sage_dense_mfma<false><<<mgrid, 256, 0, stream>>>(bufA, xB, Wt1, b1, bufB,
                                                      nullptr, nullptr, nullptr, n);

    // ---- layer 2 + head: mean2 = gather(bufB) -> bufC; out = head(dense(bufC, bufB)) ----
    gather_mean_bf<<<ggrid, 256, 0, stream>>>(bufB, rowptr, csr_src, bufC, n);
    sage_dense_mfma<true><<<mgrid, 256, 0, stream>>>(bufC, bufB, Wt2, b2, nullptr,
                                                     Wh, bh, out, n);
}

// Round 5
// 202.352 us; speedup vs baseline: 14.6724x; 1.0900x over previous
//
#include <hip/hip_runtime.h>
#include <hip/hip_bf16.h>

#define DIM 128

typedef short short8_t __attribute__((ext_vector_type(8)));
typedef float float4_t __attribute__((ext_vector_type(4)));

__device__ __forceinline__ unsigned short f2bf(float f) {
    __hip_bfloat16 h = __float2bfloat16(f);
    return *reinterpret_cast<unsigned short*>(&h);
}
__device__ __forceinline__ float bf2f(unsigned int lo16) {
    return __uint_as_float(lo16 << 16);
}

// ---------------- fused prep: zero deg + x->bf16 + weight transpose x2 ----------------
// work layout: [0, NX4)            : x float4 -> bf16 uint2
//              [NX4, NX4+NZ4)      : zero deg (int4)
//              [NX4+NZ4, +65536)   : Wt1 / Wt2 build
__global__ __launch_bounds__(256) void prep_kernel(
    const float* __restrict__ x, unsigned short* __restrict__ xB,
    int* __restrict__ deg,
    const float* __restrict__ W1l, const float* __restrict__ W1r,
    const float* __restrict__ W2l, const float* __restrict__ W2r,
    unsigned short* __restrict__ Wt1, unsigned short* __restrict__ Wt2,
    int nx4, int nz4)
{
    int idx = blockIdx.x * 256 + threadIdx.x;
    if (idx < nx4) {
        float4 v = reinterpret_cast<const float4*>(x)[idx];
        uint2 p;
        p.x = (unsigned int)f2bf(v.x) | ((unsigned int)f2bf(v.y) << 16);
        p.y = (unsigned int)f2bf(v.z) | ((unsigned int)f2bf(v.w) << 16);
        reinterpret_cast<uint2*>(xB)[idx] = p;
        return;
    }
    idx -= nx4;
    if (idx < nz4) {
        reinterpret_cast<int4*>(deg)[idx] = make_int4(0, 0, 0, 0);
        return;
    }
    idx -= nz4;
    if (idx < 65536) {
        const int which = idx >> 15;          // 0 -> Wt1, 1 -> Wt2
        const int j = idx & 32767;
        const int c = j >> 8;
        const int k = j & 255;
        const float* Wl = which ? W2l : W1l;
        const float* Wr = which ? W2r : W1r;
        unsigned short* Wt = which ? Wt2 : Wt1;
        float v = (k < DIM) ? Wl[k * DIM + c] : Wr[(k - DIM) * DIM + c];
        Wt[c * 256 + k] = f2bf(v);
    }
}

// ---------------- rank+degree: rank[e] = old count of dst ----------------
__global__ __launch_bounds__(256) void rank_kernel(
    const int* __restrict__ dst, int* __restrict__ deg,
    int* __restrict__ rank, int E)
{
    int e = blockIdx.x * 256 + threadIdx.x;
    if (e < E) rank[e] = atomicAdd(&deg[dst[e]], 1);
}

// ---------------- per-block partial sums of deg ----------------
__global__ __launch_bounds__(256) void partial_kernel(
    const int* __restrict__ deg, int* __restrict__ partial, int n)
{
    __shared__ int s[256];
    const int t = threadIdx.x;
    const int i = blockIdx.x * 256 + t;
    s[t] = (i < n) ? deg[i] : 0;
    __syncthreads();
    for (int off = 128; off > 0; off >>= 1) {
        if (t < off) s[t] += s[t + off];
        __syncthreads();
    }
    if (t == 0) partial[blockIdx.x] = s[0];
}

// ---------------- scan the block partials (nblk <= 256) ----------------
__global__ __launch_bounds__(256) void scan_partials(
    const int* __restrict__ partial, int* __restrict__ blockoff,
    int nblk, int* __restrict__ rowptr, int n)
{
    __shared__ int s[256];
    const int t = threadIdx.x;
    const int v = (t < nblk) ? partial[t] : 0;
    s[t] = v;
    __syncthreads();
    for (int off = 1; off < 256; off <<= 1) {
        int a = (t >= off) ? s[t - off] : 0;
        __syncthreads();
        s[t] += a;
        __syncthreads();
    }
    if (t < nblk) blockoff[t] = s[t] - v;     // exclusive
    if (t == 255) rowptr[n] = s[255];         // total == E
}

// ---------------- local scan -> rowptr ----------------
__global__ __launch_bounds__(256) void local_scan(
    const int* __restrict__ deg, const int* __restrict__ blockoff,
    int* __restrict__ rowptr, int n)
{
    __shared__ int s[256];
    const int t = threadIdx.x;
    const int i = blockIdx.x * 256 + t;
    const int v = (i < n) ? deg[i] : 0;
    s[t] = v;
    __syncthreads();
    for (int off = 1; off < 256; off <<= 1) {
        int a = (t >= off) ? s[t - off] : 0;
        __syncthreads();
        s[t] += a;
        __syncthreads();
    }
    if (i < n) rowptr[i] = blockoff[blockIdx.x] + s[t] - v;
}

// ---------------- atomic-free CSR fill ----------------
__global__ __launch_bounds__(256) void scatter_fill(
    const int* __restrict__ src, const int* __restrict__ dst,
    const int* __restrict__ rank, const int* __restrict__ rowptr,
    int* __restrict__ csr_src, int E)
{
    int e = blockIdx.x * 256 + threadIdx.x;
    if (e < E) csr_src[rowptr[dst[e]] + rank[e]] = src[e];
}

// ---------------- gather mean (bf16): one wave per node, uint2/lane, 2 rows per load ----------------
__global__ __launch_bounds__(256) void gather_mean_bf(
    const unsigned short* __restrict__ xb, const int* __restrict__ rowptr,
    const int* __restrict__ csr_src, unsigned short* __restrict__ mean, int n)
{
    const int node = (blockIdx.x * 256 + threadIdx.x) >> 6;
    const int lane = threadIdx.x & 63;
    if (node >= n) return;
    const int beg = rowptr[node], end = rowptr[node + 1];
    const int half = lane >> 5;     // which row of the pair
    const int col  = lane & 31;     // uint2 column (4 bf16 features)
    const uint2* xv = (const uint2*)xb;      // 32 uint2 per row
    float a0 = 0.f, a1 = 0.f, a2 = 0.f, a3 = 0.f;
    int i = beg;
    for (; i + 8 <= end; i += 8) {
        int e0 = csr_src[i + half];
        int e1 = csr_src[i + 2 + half];
        int e2 = csr_src[i + 4 + half];
        int e3 = csr_src[i + 6 + half];
        uint2 v0 = xv[(size_t)e0 * 32 + col];
        uint2 v1 = xv[(size_t)e1 * 32 + col];
        uint2 v2 = xv[(size_t)e2 * 32 + col];
        uint2 v3 = xv[(size_t)e3 * 32 + col];
        a0 += bf2f(v0.x & 0xffffu) + bf2f(v1.x & 0xffffu) + bf2f(v2.x & 0xffffu) + bf2f(v3.x & 0xffffu);
        a1 += bf2f(v0.x >> 16)     + bf2f(v1.x >> 16)     + bf2f(v2.x >> 16)     + bf2f(v3.x >> 16);
        a2 += bf2f(v0.y & 0xffffu) + bf2f(v1.y & 0xffffu) + bf2f(v2.y & 0xffffu) + bf2f(v3.y & 0xffffu);
        a3 += bf2f(v0.y >> 16)     + bf2f(v1.y >> 16)     + bf2f(v2.y >> 16)     + bf2f(v3.y >> 16);
    }
    for (; i + 2 <= end; i += 2) {
        int e = csr_src[i + half];
        uint2 v = xv[(size_t)e * 32 + col];
        a0 += bf2f(v.x & 0xffffu);
        a1 += bf2f(v.x >> 16);
        a2 += bf2f(v.y & 0xffffu);
        a3 += bf2f(v.y >> 16);
    }
    if (i < end && half == 0) {     // odd tail: half-wave handles last edge
        int e = csr_src[i];
        uint2 v = xv[(size_t)e * 32 + col];
        a0 += bf2f(v.x & 0xffffu);
        a1 += bf2f(v.x >> 16);
        a2 += bf2f(v.y & 0xffffu);
        a3 += bf2f(v.y >> 16);
    }
    // combine the two half-wave partials
    a0 += __shfl_xor(a0, 32, 64);
    a1 += __shfl_xor(a1, 32, 64);
    a2 += __shfl_xor(a2, 32, 64);
    a3 += __shfl_xor(a3, 32, 64);
    if (half == 0) {
        const float r = 1.0f / fmaxf((float)(end - beg), 1.0f);
        uint2 o;
        o.x = (unsigned int)f2bf(a0 * r) | ((unsigned int)f2bf(a1 * r) << 16);
        o.y = (unsigned int)f2bf(a2 * r) | ((unsigned int)f2bf(a3 * r) << 16);
        ((uint2*)mean)[(size_t)node * 32 + col] = o;
    }
}

// ---------------- MFMA SAGE dense: relu([mean|x] @ [Wl;Wr] + b), optional fused head ----------------
// 64 nodes/block, 4 waves. A staged bf16 in LDS, row padded to 264 shorts.
template <bool FUSE_HEAD>
__global__ __launch_bounds__(256) void sage_dense_mfma(
    const unsigned short* __restrict__ meanB, const unsigned short* __restrict__ xinB,
    const unsigned short* __restrict__ Wt,    // [128][256] bf16, feat-major
    const float* __restrict__ bias,
    unsigned short* __restrict__ outB,        // !FUSE_HEAD: bf16 [n,128]
    const float* __restrict__ Wh, const float* __restrict__ bh,
    float* __restrict__ outH,                 // FUSE_HEAD: fp32 [n,2]
    int n)
{
    __shared__ unsigned short A_s[64 * 264];   // 33792 B
    const int t = threadIdx.x;
    const int node0 = blockIdx.x * 64;

    // stage A = [mean | x] (bf16): 64 rows x 32 chunks of 16B
    for (int idx = t; idx < 2048; idx += 256) {
        const int nd = idx >> 5;
        const int c  = idx & 31;
        const int node = node0 + nd;
        uint4 p = make_uint4(0, 0, 0, 0);
        if (node < n) {
            p = (c < 16) ? reinterpret_cast<const uint4*>(meanB)[(size_t)node * 16 + c]
                         : reinterpret_cast<const uint4*>(xinB)[(size_t)node * 16 + (c - 16)];
        }
        *reinterpret_cast<uint4*>((char*)A_s + nd * 528 + c * 16) = p;
    }
    __syncthreads();

    const int wave = t >> 6;
    const int lane = t & 63;
    const int r = lane & 15;       // node-in-16 for A / feat-in-16 for B / D col
    const int u = lane >> 4;       // k-block

    const char* a_base = (const char*)A_s + (wave * 16 + r) * 528 + u * 16;

    float4_t acc[8];
#pragma unroll
    for (int ft = 0; ft < 8; ++ft) acc[ft] = (float4_t){0.f, 0.f, 0.f, 0.f};

#pragma unroll
    for (int kk = 0; kk < 8; ++kk) {
        const short8_t a = *reinterpret_cast<const short8_t*>(a_base + kk * 64);
#pragma unroll
        for (int ft = 0; ft < 8; ++ft) {
            const short8_t b = *reinterpret_cast<const short8_t*>(
                &Wt[(ft * 16 + r) * 256 + kk * 32 + u * 8]);
            acc[ft] = __builtin_amdgcn_mfma_f32_16x16x32_bf16(a, b, acc[ft], 0, 0, 0);
        }
    }

    if (!FUSE_HEAD) {
#pragma unroll
        for (int ft = 0; ft < 8; ++ft) {
            const int feat = ft * 16 + r;
            const float bv = bias[feat];
#pragma unroll
            for (int j = 0; j < 4; ++j) {
                const int node = node0 + wave * 16 + u * 4 + j;
                if (node < n) {
                    outB[(size_t)node * DIM + feat] = f2bf(fmaxf(acc[ft][j] + bv, 0.0f));
                }
            }
        }
    } else {
        float p0[4] = {0.f, 0.f, 0.f, 0.f};
        float p1[4] = {0.f, 0.f, 0.f, 0.f};
#pragma unroll
        for (int ft = 0; ft < 8; ++ft) {
            const int feat = ft * 16 + r;
            const float bv = bias[feat];
            const float w0 = Wh[feat * 2 + 0];
            const float w1 = Wh[feat * 2 + 1];
#pragma unroll
            for (int j = 0; j < 4; ++j) {
                const float h = fmaxf(acc[ft][j] + bv, 0.0f);
                p0[j] += h * w0;
                p1[j] += h * w1;
            }
        }
#pragma unroll
        for (int off = 1; off < 16; off <<= 1) {
#pragma unroll
            for (int j = 0; j < 4; ++j) {
                p0[j] += __shfl_xor(p0[j], off, 64);
                p1[j] += __shfl_xor(p1[j], off, 64);
            }
        }
        if (r == 0) {
            const float bh0 = bh[0], bh1 = bh[1];
#pragma unroll
            for (int j = 0; j < 4; ++j) {
                const int node = node0 + wave * 16 + u * 4 + j;
                if (node < n) {
                    outH[(size_t)node * 2 + 0] = p0[j] + bh0;
                    outH[(size_t)node * 2 + 1] = p1[j] + bh1;
                }
            }
        }
    }
}

extern "C" void kernel_launch(void* const* d_in, const int* in_sizes, int n_in,
                              void* d_out, int out_size, void* d_ws, size_t ws_size,
                              hipStream_t stream) {
    const float* x    = (const float*)d_in[0];
    const int*   ei   = (const int*)d_in[1];
    const float* W1l  = (const float*)d_in[2];
    const float* W1r  = (const float*)d_in[3];
    const float* b1   = (const float*)d_in[4];
    const float* W2l  = (const float*)d_in[5];
    const float* W2r  = (const float*)d_in[6];
    const float* b2   = (const float*)d_in[7];
    const float* Wh   = (const float*)d_in[8];
    const float* bh   = (const float*)d_in[9];
    float* out = (float*)d_out;

    const int n = in_sizes[0] / DIM;      // 50000
    const int E = in_sizes[1] / 2;        // 800000
    const int* src = ei;
    const int* dst = ei + E;

    auto align512 = [](size_t v) { return (v + 511) & ~(size_t)511; };
    char* ws = (char*)d_ws;
    size_t off = 0;
    int* deg      = (int*)(ws + off); off = align512(off + (size_t)n * 4);
    int* rowptr   = (int*)(ws + off); off = align512(off + (size_t)(n + 1) * 4);
    int* rank     = (int*)(ws + off); off = align512(off + (size_t)E * 4);
    int* partial  = (int*)(ws + off); off = align512(off + 256 * 4);
    int* blockoff = (int*)(ws + off); off = align512(off + 256 * 4);
    int* csr_src  = (int*)(ws + off); off = align512(off + (size_t)E * 4);
    unsigned short* Wt1 = (unsigned short*)(ws + off); off = align512(off + (size_t)32768 * 2);
    unsigned short* Wt2 = (unsigned short*)(ws + off); off = align512(off + (size_t)32768 * 2);
    unsigned short* xB   = (unsigned short*)(ws + off); off = align512(off + (size_t)n * DIM * 2);
    unsigned short* bufA = (unsigned short*)(ws + off); off = align512(off + (size_t)n * DIM * 2);
    unsigned short* bufB = (unsigned short*)(ws + off); off = align512(off + (size_t)n * DIM * 2);
    unsigned short* bufC = (unsigned short*)(ws + off); off = align512(off + (size_t)n * DIM * 2);

    const int nblk  = (n + 255) / 256;        // 196
    const int egrid = (E + 255) / 256;
    const int ggrid = (n + 3) / 4;            // 4 waves/block, 1 node/wave
    const int mgrid = (n + 63) / 64;          // MFMA dense blocks

    const int nx4 = n * DIM / 4;              // 1.6M
    const int nz4 = n / 4;                    // 12500
    const int pwork = nx4 + nz4 + 65536;
    const int pgrid = (pwork + 255) / 256;

    // ---- fused prep: zero deg + x->bf16 + Wt1/Wt2 ----
    prep_kernel<<<pgrid, 256, 0, stream>>>(x, xB, deg, W1l, W1r, W2l, W2r,
                                           Wt1, Wt2, nx4, nz4);

    // ---- build CSR (atomic rank pass + scans + atomic-free fill) ----
    rank_kernel<<<egrid, 256, 0, stream>>>(dst, deg, rank, E);
    partial_kernel<<<nblk, 256, 0, stream>>>(deg, partial, n);
    scan_partials<<<1, 256, 0, stream>>>(partial, blockoff, nblk, rowptr, n);
    local_scan<<<nblk, 256, 0, stream>>>(deg, blockoff, rowptr, n);
    scatter_fill<<<egrid, 256, 0, stream>>>(src, dst, rank, rowptr, csr_src, E);

    // ---- layer 1: mean1 -> bufA; h1 = dense(bufA, xB) -> bufB (bf16) ----
    gather_mean_bf<<<ggrid, 256, 0, stream>>>(xB, rowptr, csr_src, bufA, n);
    sage_dense_mfma<false><<<mgrid, 256, 0, stream>>>(bufA, xB, Wt1, b1, bufB,
                                                      nullptr, nullptr, nullptr, n);

    // ---- layer 2 + head: mean2 = gather(bufB) -> bufC; out = head(dense(bufC, bufB)) ----
    gather_mean_bf<<<ggrid, 256, 0, stream>>>(bufB, rowptr, csr_src, bufC, n);
    sage_dense_mfma<true><<<mgrid, 256, 0, stream>>>(bufC, bufB, Wt2, b2, nullptr,
                                                     Wh, bh, out, n);
}